// Round 4
// baseline (5518.043 us; speedup 1.0000x reference)
//
#include <hip/hip_runtime.h>
#include <cstdint>

// ---------------------------------------------------------------------------
// 2-layer tanh RNN (B=256,S=2048,D=64,H=256).
// R2: LDS-pipe bound (208 b128 reads + 256 b16 writes per CU-step).
// R3 (this design, fixed compile): (a) merged single-barrier phase (h0[p] and
// h1[p-1] concurrent; h0[p-1] fragments shared by Whh0 & Wih1 products),
// (b) 4 waves x 4 n-tiles (per-CU LDS reads 208->64), (c) x-projection hoisted
// to a parallel pre-pass writing pre0 (bf16, C-fragment layout) to d_ws.
// R3 compile fix: no const arrays of LDS pointers (addrspacecast static-init
// error) — ping-pong buffers addressed via integer byte offsets into smem.
// ---------------------------------------------------------------------------

#define S_LEN 2048
#define DIN   64
#define HDIM  256

typedef __attribute__((ext_vector_type(8))) short bf16x8;
typedef __attribute__((ext_vector_type(4))) float f32x4;

__device__ __forceinline__ short f2bf(float f) {
  unsigned u = __builtin_bit_cast(unsigned, f);
  u += 0x7FFFu + ((u >> 16) & 1u);           // RNE
  return (short)(u >> 16);
}
__device__ __forceinline__ float bf2f(unsigned short h) {
  return __builtin_bit_cast(float, ((unsigned)h) << 16);
}
__device__ __forceinline__ bf16x8 cvt8(f32x4 a, f32x4 b) {
  bf16x8 r;
  r[0]=f2bf(a[0]); r[1]=f2bf(a[1]); r[2]=f2bf(a[2]); r[3]=f2bf(a[3]);
  r[4]=f2bf(b[0]); r[5]=f2bf(b[1]); r[6]=f2bf(b[2]); r[7]=f2bf(b[3]);
  return r;
}
__device__ __forceinline__ bf16x8 load8cvt(const float* p) {
  f32x4 a = *(const f32x4*)p;
  f32x4 b = *(const f32x4*)(p + 4);
  return cvt8(a, b);
}
__device__ __forceinline__ f32x4 mfma16(bf16x8 a, bf16x8 b, f32x4 c) {
  return __builtin_amdgcn_mfma_f32_16x16x32_bf16(a, b, c, 0, 0, 0);
}
// tanh(x) = 1 - 2/(1+e^{2x}); saturates correctly at +-inf. 2 trans ops.
__device__ __forceinline__ float fast_tanh(float x) {
  float e = __expf(2.0f * x);
  float r = __builtin_amdgcn_rcpf(1.0f + e);
  return 1.0f - 2.0f * r;
}
// fragment-major offset of element (k, row m) in a 16x256 bf16 tile; a wave's
// A-fragment read for k-tile kt is 16B at kt*1024 + lane*16 (conflict-free).
__device__ __forceinline__ int frag_off(int k, int m) {
  return ((k >> 5) << 10) | (((k >> 3) & 3) << 8) | (m << 4) | ((k & 7) << 1);
}
// unpack bf16x4 (as uint2) -> f32x4 accumulator init (2 ops/value)
__device__ __forceinline__ f32x4 unpk4(uint2 v) {
  f32x4 a;
  a[0] = __builtin_bit_cast(float, v.x << 16);
  a[1] = __builtin_bit_cast(float, v.x & 0xFFFF0000u);
  a[2] = __builtin_bit_cast(float, v.y << 16);
  a[3] = __builtin_bit_cast(float, v.y & 0xFFFF0000u);
  return a;
}

// ============ pre-pass: pre0[tile][t][ntile][lane] = x W_ih0^T + b (C-layout)
__global__ void __launch_bounds__(256)
x_proj(const float* __restrict__ x, const float* __restrict__ Wih0,
       const float* __restrict__ bih0, const float* __restrict__ bhh0,
       uint2* __restrict__ pre0) {
  const int tid = threadIdx.x, w = tid >> 6, l = tid & 63;
  const int lm = l & 15, lq = l >> 4;
  const int tile = blockIdx.x, tch = blockIdx.y;

  bf16x8 wih[4][2]; float bias[4];
#pragma unroll
  for (int i = 0; i < 4; ++i) {
    int n = ((w * 4 + i) << 4) + lm;
    wih[i][0] = load8cvt(Wih0 + n * DIN + lq * 8);
    wih[i][1] = load8cvt(Wih0 + n * DIN + 32 + lq * 8);
    bias[i] = bih0[n] + bhh0[n];
  }
  const float* xb = x + (size_t)(tile * 16 + lm) * (S_LEN * DIN) + lq * 8;
  for (int tt = 0; tt < 16; ++tt) {
    int t = tch * 16 + tt;
    const float* xp = xb + (size_t)t * DIN;
    bf16x8 xa0 = load8cvt(xp);
    bf16x8 xa1 = load8cvt(xp + 32);
    uint2* dst = pre0 + ((size_t)(tile * S_LEN + t) * 16 + w * 4) * 64 + l;
#pragma unroll
    for (int i = 0; i < 4; ++i) {
      f32x4 a = {bias[i], bias[i], bias[i], bias[i]};
      a = mfma16(xa0, wih[i][0], a);
      a = mfma16(xa1, wih[i][1], a);
      uint2 pk;
      pk.x = (unsigned)(unsigned short)f2bf(a[0]) | ((unsigned)(unsigned short)f2bf(a[1]) << 16);
      pk.y = (unsigned)(unsigned short)f2bf(a[2]) | ((unsigned)(unsigned short)f2bf(a[3]) << 16);
      dst[(size_t)i * 64] = pk;
    }
  }
}

// ============ persistent recurrence, pre0 path: 16 WGs x 256 thr (4 waves) ===
// smem layout (byte offsets): h0 ping 0, h0 pong 8192, h1 ping 16384,
// h1 pong 24576, epilogue scratch 32768.
__global__ void __launch_bounds__(256, 1)
rnn_pre(const float* __restrict__ Whh0, const float* __restrict__ Wih1,
        const float* __restrict__ Whh1, const float* __restrict__ bih1,
        const float* __restrict__ bhh1, const float* __restrict__ Wout,
        const float* __restrict__ bout, const uint2* __restrict__ pre0,
        float* __restrict__ out) {
  __shared__ __align__(16) char smem[33792];

  const int tid = threadIdx.x, w = tid >> 6, l = tid & 63;
  const int lm = l & 15, lq = l >> 4;
  const int tile = blockIdx.x;

  // weights: 96 register-resident B-fragments (4 n-tiles/wave)
  bf16x8 whh0[4][8], wih1[4][8], whh1[4][8];
  float bias1[4];
#pragma unroll
  for (int i = 0; i < 4; ++i) {
    int n = ((w * 4 + i) << 4) + lm;
#pragma unroll
    for (int kt = 0; kt < 8; ++kt) {
      whh0[i][kt] = load8cvt(Whh0 + n * HDIM + kt * 32 + lq * 8);
      wih1[i][kt] = load8cvt(Wih1 + n * HDIM + kt * 32 + lq * 8);
      whh1[i][kt] = load8cvt(Whh1 + n * HDIM + kt * 32 + lq * 8);
    }
    bias1[i] = bih1[n] + bhh1[n];
  }
  // zero h1 pong (= h1[-1] at 24576); other buffers written before first read
  ((f32x4*)(smem + 24576))[tid] = (f32x4){0.f, 0.f, 0.f, 0.f};
  ((f32x4*)(smem + 24576))[tid + 256] = (f32x4){0.f, 0.f, 0.f, 0.f};

  const uint2* pbase = pre0 + (size_t)tile * (S_LEN * 16 * 64) + (w * 4) * 64 + l;
  uint2 cu[4], nu[4];
#pragma unroll
  for (int i = 0; i < 4; ++i) cu[i] = pbase[(size_t)i * 64];          // pre0[0]
#pragma unroll
  for (int i = 0; i < 4; ++i) nu[i] = pbase[1024 + (size_t)i * 64];   // pre0[1]

  // ---- phase 0 (peeled): h0[0] = tanh(pre0[0]) into h0 ping (offset 0) ----
#pragma unroll
  for (int i = 0; i < 4; ++i) {
    f32x4 a = unpk4(cu[i]);
    int n = ((w * 4 + i) << 4) + lm;
#pragma unroll
    for (int r = 0; r < 4; ++r)
      *(short*)(smem + frag_off(n, (lq << 2) + r)) = f2bf(fast_tanh(a[r]));
    cu[i] = nu[i];
  }
  __syncthreads();

  // ---- main phases p = 1 .. S-1: h0[p] and h1[p-1] concurrently -----------
  for (int p = 1; p < S_LEN; ++p) {
    const int h0r_o = ((p - 1) & 1) * 8192;          // h0[p-1]
    const int h0w_o = (p & 1) * 8192;                // h0[p]
    const int h1r_o = 16384 + (p & 1) * 8192;        // h1[p-2]
    const int h1w_o = 16384 + ((p - 1) & 1) * 8192;  // h1[p-1]

    // prefetch pre0[p+1] (clamped at the tail; value unused at p = S-1)
    {
      int tn = (p + 1 < S_LEN) ? p + 1 : S_LEN - 1;
      const uint2* np = pbase + (size_t)tn * 1024;
#pragma unroll
      for (int i = 0; i < 4; ++i) nu[i] = np[(size_t)i * 64];
    }
    f32x4 a0 = unpk4(cu[0]), a1 = unpk4(cu[1]), a2 = unpk4(cu[2]), a3 = unpk4(cu[3]);
    f32x4 c0 = {bias1[0], bias1[0], bias1[0], bias1[0]};
    f32x4 c1 = {bias1[1], bias1[1], bias1[1], bias1[1]};
    f32x4 c2 = {bias1[2], bias1[2], bias1[2], bias1[2]};
    f32x4 c3 = {bias1[3], bias1[3], bias1[3], bias1[3]};

#pragma unroll
    for (int kt = 0; kt < 8; ++kt) {       // shared h0[p-1] fragments
      bf16x8 hf = *(const bf16x8*)(smem + h0r_o + kt * 1024 + (l << 4));
      a0 = mfma16(hf, whh0[0][kt], a0);
      a1 = mfma16(hf, whh0[1][kt], a1);
      a2 = mfma16(hf, whh0[2][kt], a2);
      a3 = mfma16(hf, whh0[3][kt], a3);
      c0 = mfma16(hf, wih1[0][kt], c0);
      c1 = mfma16(hf, wih1[1][kt], c1);
      c2 = mfma16(hf, wih1[2][kt], c2);
      c3 = mfma16(hf, wih1[3][kt], c3);
    }
#pragma unroll
    for (int kt = 0; kt < 8; ++kt) {       // h1[p-2] fragments
      bf16x8 hf = *(const bf16x8*)(smem + h1r_o + kt * 1024 + (l << 4));
      c0 = mfma16(hf, whh1[0][kt], c0);
      c1 = mfma16(hf, whh1[1][kt], c1);
      c2 = mfma16(hf, whh1[2][kt], c2);
      c3 = mfma16(hf, whh1[3][kt], c3);
    }
#pragma unroll
    for (int i = 0; i < 4; ++i) {
      f32x4 a = i == 0 ? a0 : i == 1 ? a1 : i == 2 ? a2 : a3;
      f32x4 c = i == 0 ? c0 : i == 1 ? c1 : i == 2 ? c2 : c3;
      int n = ((w * 4 + i) << 4) + lm;
#pragma unroll
      for (int r = 0; r < 4; ++r) {
        int fo = frag_off(n, (lq << 2) + r);
        *(short*)(smem + h0w_o + fo) = f2bf(fast_tanh(a[r]));
        *(short*)(smem + h1w_o + fo) = f2bf(fast_tanh(c[r]));
      }
      cu[i] = nu[i];
    }
    __syncthreads();
  }

  // ---- phase S (peeled): h1[S-1] ------------------------------------------
  {
    const int h0r_o = ((S_LEN - 1) & 1) * 8192;
    const int h1r_o = 16384 + (S_LEN & 1) * 8192;
    const int h1w_o = 16384 + ((S_LEN - 1) & 1) * 8192;
    f32x4 c0 = {bias1[0], bias1[0], bias1[0], bias1[0]};
    f32x4 c1 = {bias1[1], bias1[1], bias1[1], bias1[1]};
    f32x4 c2 = {bias1[2], bias1[2], bias1[2], bias1[2]};
    f32x4 c3 = {bias1[3], bias1[3], bias1[3], bias1[3]};
#pragma unroll
    for (int kt = 0; kt < 8; ++kt) {
      bf16x8 hf = *(const bf16x8*)(smem + h0r_o + kt * 1024 + (l << 4));
      c0 = mfma16(hf, wih1[0][kt], c0);
      c1 = mfma16(hf, wih1[1][kt], c1);
      c2 = mfma16(hf, wih1[2][kt], c2);
      c3 = mfma16(hf, wih1[3][kt], c3);
    }
#pragma unroll
    for (int kt = 0; kt < 8; ++kt) {
      bf16x8 hf = *(const bf16x8*)(smem + h1r_o + kt * 1024 + (l << 4));
      c0 = mfma16(hf, whh1[0][kt], c0);
      c1 = mfma16(hf, whh1[1][kt], c1);
      c2 = mfma16(hf, whh1[2][kt], c2);
      c3 = mfma16(hf, whh1[3][kt], c3);
    }
#pragma unroll
    for (int i = 0; i < 4; ++i) {
      f32x4 c = i == 0 ? c0 : i == 1 ? c1 : i == 2 ? c2 : c3;
      int n = ((w * 4 + i) << 4) + lm;
#pragma unroll
      for (int r = 0; r < 4; ++r)
        *(short*)(smem + h1w_o + frag_off(n, (lq << 2) + r)) = f2bf(fast_tanh(c[r]));
    }
    __syncthreads();
  }

  // ---- epilogue: out = sigmoid(h1_last @ W_out^T + b_out) -----------------
  // h1[S-1] lives in h1 pong (offset 16384 + ((S-1)&1)*8192 = 24576).
  {
    int m = tid >> 4, j = tid & 15;
    float s = 0.f;
#pragma unroll
    for (int kk = 0; kk < 16; ++kk) {
      int k = j * 16 + kk;
      s += bf2f(*(unsigned short*)(smem + 24576 + frag_off(k, m))) * Wout[k];
    }
    ((float*)(smem + 32768))[(m << 4) + j] = s;
  }
  __syncthreads();
  if (tid < 16) {
    float s = 0.f;
#pragma unroll
    for (int j = 0; j < 16; ++j) s += ((float*)(smem + 32768))[(tid << 4) + j];
    s += bout[0];
    out[(tile << 4) + tid] = 1.f / (1.f + __expf(-s));
  }
}

// ============ fallback (small ws): R2 kernel shape, 8 waves, inline x =======
// smem: h0 ping 0, h0 pong 8192, h1 ping 16384, h1 pong 24576,
// xs ping 32768, xs pong 34816, epilogue 36864.
__global__ void __launch_bounds__(512)
rnn_inline(const float* __restrict__ x,
           const float* __restrict__ Wih0, const float* __restrict__ Whh0,
           const float* __restrict__ bih0, const float* __restrict__ bhh0,
           const float* __restrict__ Wih1, const float* __restrict__ Whh1,
           const float* __restrict__ bih1, const float* __restrict__ bhh1,
           const float* __restrict__ Wout, const float* __restrict__ bout,
           float* __restrict__ out) {
  __shared__ __align__(16) char smem[37888];

  const int tid = threadIdx.x, w = tid >> 6, l = tid & 63;
  const int lm = l & 15, lq = l >> 4;
  const int tile = blockIdx.x;

  bf16x8 whh0[2][8], wih0[2][2], wih1[2][8], whh1[2][8];
  float bias0[2], bias1[2];
#pragma unroll
  for (int i = 0; i < 2; ++i) {
    int n = ((w * 2 + i) << 4) + lm;
#pragma unroll
    for (int kt = 0; kt < 8; ++kt) {
      whh0[i][kt] = load8cvt(Whh0 + n * HDIM + kt * 32 + lq * 8);
      wih1[i][kt] = load8cvt(Wih1 + n * HDIM + kt * 32 + lq * 8);
      whh1[i][kt] = load8cvt(Whh1 + n * HDIM + kt * 32 + lq * 8);
    }
    wih0[i][0] = load8cvt(Wih0 + n * DIN + lq * 8);
    wih0[i][1] = load8cvt(Wih0 + n * DIN + 32 + lq * 8);
    bias0[i] = bih0[n] + bhh0[n];
    bias1[i] = bih1[n] + bhh1[n];
  }
  ((f32x4*)(smem + 24576))[tid] = (f32x4){0.f, 0.f, 0.f, 0.f};  // h1[-1] = 0
  const float* xrow = x + (size_t)(tile * 16 + lm) * (S_LEN * DIN);
  if (w < 2)
    *(bf16x8*)(smem + 32768 + w * 1024 + (l << 4)) = load8cvt(xrow + w * 32 + lq * 8);
  __syncthreads();

  // phase 0: h0[0] = tanh(x0 Wih0^T + b0) into h0 ping (0)
  {
    f32x4 a0 = {bias0[0], bias0[0], bias0[0], bias0[0]};
    f32x4 a1 = {bias0[1], bias0[1], bias0[1], bias0[1]};
    bf16x8 xa0 = *(const bf16x8*)(smem + 32768 + (l << 4));
    bf16x8 xa1 = *(const bf16x8*)(smem + 32768 + 1024 + (l << 4));
    a0 = mfma16(xa0, wih0[0][0], a0); a0 = mfma16(xa1, wih0[0][1], a0);
    a1 = mfma16(xa0, wih0[1][0], a1); a1 = mfma16(xa1, wih0[1][1], a1);
    if (w < 2)
      *(bf16x8*)(smem + 34816 + w * 1024 + (l << 4)) = load8cvt(xrow + DIN + w * 32 + lq * 8);
#pragma unroll
    for (int i = 0; i < 2; ++i) {
      f32x4 a = i ? a1 : a0;
      int n = ((w * 2 + i) << 4) + lm;
#pragma unroll
      for (int r = 0; r < 4; ++r)
        *(short*)(smem + frag_off(n, (lq << 2) + r)) = f2bf(fast_tanh(a[r]));
    }
    __syncthreads();
  }

  for (int p = 1; p < S_LEN; ++p) {
    const int h0r_o = ((p - 1) & 1) * 8192;
    const int h0w_o = (p & 1) * 8192;
    const int h1r_o = 16384 + (p & 1) * 8192;
    const int h1w_o = 16384 + ((p - 1) & 1) * 8192;
    const int xsr_o = 32768 + (p & 1) * 2048;
    const int xsw_o = 32768 + ((p + 1) & 1) * 2048;

    f32x4 xl0, xl1;
    const bool hx = (w < 2) && (p + 1 < S_LEN);
    if (hx) {
      const float* xp = xrow + (size_t)(p + 1) * DIN + w * 32 + lq * 8;
      xl0 = *(const f32x4*)xp; xl1 = *(const f32x4*)(xp + 4);
    }
    f32x4 a0 = {bias0[0], bias0[0], bias0[0], bias0[0]};
    f32x4 a1 = {bias0[1], bias0[1], bias0[1], bias0[1]};
    f32x4 c0 = {bias1[0], bias1[0], bias1[0], bias1[0]};
    f32x4 c1 = {bias1[1], bias1[1], bias1[1], bias1[1]};
#pragma unroll
    for (int kt = 0; kt < 8; ++kt) {
      bf16x8 hf = *(const bf16x8*)(smem + h0r_o + kt * 1024 + (l << 4));
      a0 = mfma16(hf, whh0[0][kt], a0);
      a1 = mfma16(hf, whh0[1][kt], a1);
      c0 = mfma16(hf, wih1[0][kt], c0);
      c1 = mfma16(hf, wih1[1][kt], c1);
    }
    {
      bf16x8 xa0 = *(const bf16x8*)(smem + xsr_o + (l << 4));
      bf16x8 xa1 = *(const bf16x8*)(smem + xsr_o + 1024 + (l << 4));
      a0 = mfma16(xa0, wih0[0][0], a0); a0 = mfma16(xa1, wih0[0][1], a0);
      a1 = mfma16(xa0, wih0[1][0], a1); a1 = mfma16(xa1, wih0[1][1], a1);
    }
#pragma unroll
    for (int kt = 0; kt < 8; ++kt) {
      bf16x8 hf = *(const bf16x8*)(smem + h1r_o + kt * 1024 + (l << 4));
      c0 = mfma16(hf, whh1[0][kt], c0);
      c1 = mfma16(hf, whh1[1][kt], c1);
    }
    if (hx) *(bf16x8*)(smem + xsw_o + w * 1024 + (l << 4)) = cvt8(xl0, xl1);
#pragma unroll
    for (int i = 0; i < 2; ++i) {
      f32x4 a = i ? a1 : a0;
      f32x4 c = i ? c1 : c0;
      int n = ((w * 2 + i) << 4) + lm;
#pragma unroll
      for (int r = 0; r < 4; ++r) {
        int fo = frag_off(n, (lq << 2) + r);
        *(short*)(smem + h0w_o + fo) = f2bf(fast_tanh(a[r]));
        *(short*)(smem + h1w_o + fo) = f2bf(fast_tanh(c[r]));
      }
    }
    __syncthreads();
  }
  // phase S: h1[S-1]
  {
    const int h0r_o = ((S_LEN - 1) & 1) * 8192;
    const int h1r_o = 16384 + (S_LEN & 1) * 8192;
    const int h1w_o = 16384 + ((S_LEN - 1) & 1) * 8192;
    f32x4 c0 = {bias1[0], bias1[0], bias1[0], bias1[0]};
    f32x4 c1 = {bias1[1], bias1[1], bias1[1], bias1[1]};
#pragma unroll
    for (int kt = 0; kt < 8; ++kt) {
      bf16x8 hf = *(const bf16x8*)(smem + h0r_o + kt * 1024 + (l << 4));
      c0 = mfma16(hf, wih1[0][kt], c0);
      c1 = mfma16(hf, wih1[1][kt], c1);
    }
#pragma unroll
    for (int kt = 0; kt < 8; ++kt) {
      bf16x8 hf = *(const bf16x8*)(smem + h1r_o + kt * 1024 + (l << 4));
      c0 = mfma16(hf, whh1[0][kt], c0);
      c1 = mfma16(hf, whh1[1][kt], c1);
    }
#pragma unroll
    for (int i = 0; i < 2; ++i) {
      f32x4 c = i ? c1 : c0;
      int n = ((w * 2 + i) << 4) + lm;
#pragma unroll
      for (int r = 0; r < 4; ++r)
        *(short*)(smem + h1w_o + frag_off(n, (lq << 2) + r)) = f2bf(fast_tanh(c[r]));
    }
    __syncthreads();
  }
  if (tid < 256) {
    int m = tid >> 4, j = tid & 15;
    float s = 0.f;
#pragma unroll
    for (int kk = 0; kk < 16; ++kk) {
      int k = j * 16 + kk;
      s += bf2f(*(unsigned short*)(smem + 24576 + frag_off(k, m))) * Wout[k];
    }
    ((float*)(smem + 36864))[(m << 4) + j] = s;
  }
  __syncthreads();
  if (tid < 16) {
    float s = 0.f;
#pragma unroll
    for (int j = 0; j < 16; ++j) s += ((float*)(smem + 36864))[(tid << 4) + j];
    s += bout[0];
    out[(tile << 4) + tid] = 1.f / (1.f + __expf(-s));
  }
}

extern "C" void kernel_launch(void* const* d_in, const int* in_sizes, int n_in,
                              void* d_out, int out_size, void* d_ws, size_t ws_size,
                              hipStream_t stream) {
  (void)in_sizes; (void)n_in; (void)out_size;
  const float* x    = (const float*)d_in[0];
  const float* Wih0 = (const float*)d_in[1];
  const float* Whh0 = (const float*)d_in[2];
  const float* bih0 = (const float*)d_in[3];
  const float* bhh0 = (const float*)d_in[4];
  const float* Wih1 = (const float*)d_in[5];
  const float* Whh1 = (const float*)d_in[6];
  const float* bih1 = (const float*)d_in[7];
  const float* bhh1 = (const float*)d_in[8];
  const float* Wout = (const float*)d_in[9];
  const float* bout = (const float*)d_in[10];

  const size_t PRE_BYTES = (size_t)16 * S_LEN * 16 * 64 * 8;  // 268 MB
  if (ws_size >= PRE_BYTES) {
    x_proj<<<dim3(16, 128), dim3(256), 0, stream>>>(x, Wih0, bih0, bhh0,
                                                    (uint2*)d_ws);
    rnn_pre<<<dim3(16), dim3(256), 0, stream>>>(
        Whh0, Wih1, Whh1, bih1, bhh1, Wout, bout, (const uint2*)d_ws,
        (float*)d_out);
  } else {
    rnn_inline<<<dim3(16), dim3(512), 0, stream>>>(
        x, Wih0, Whh0, bih0, bhh0, Wih1, Whh1, bih1, bhh1, Wout, bout,
        (float*)d_out);
  }
}

// Round 5
// 3199.606 us; speedup vs baseline: 1.7246x; 1.7246x over previous
//
#include <hip/hip_runtime.h>
#include <cstdint>

// ---------------------------------------------------------------------------
// 2-layer tanh RNN (B=256,S=2048,D=64,H=256).
// R2/R4 post-mortem: both ~6100 cyc/step regardless of structure. Active-CU
// counters (VALUBusy ~41%, MfmaUtil ~25% => ~16cyc/MFMA) implicate AGPR
// shuffling from register over-pressure (R4: 384 weight VGPRs vs 256 cap;
// R2: 128-VGPR compiler cap). R5: 8 waves x 2 n-tiles -> 192 weight VGPRs,
// __launch_bounds__(512,2) grants 256/wave => pure-VGPR weights, and all LDS
// addressing folded into constant offset immediates (parity-unrolled loop).
// ---------------------------------------------------------------------------

#define S_LEN 2048
#define DIN   64
#define HDIM  256

typedef __attribute__((ext_vector_type(8))) short bf16x8;
typedef __attribute__((ext_vector_type(4))) float f32x4;

__device__ __forceinline__ short f2bf(float f) {
  unsigned u = __builtin_bit_cast(unsigned, f);
  u += 0x7FFFu + ((u >> 16) & 1u);           // RNE
  return (short)(u >> 16);
}
__device__ __forceinline__ float bf2f(unsigned short h) {
  return __builtin_bit_cast(float, ((unsigned)h) << 16);
}
__device__ __forceinline__ bf16x8 cvt8(f32x4 a, f32x4 b) {
  bf16x8 r;
  r[0]=f2bf(a[0]); r[1]=f2bf(a[1]); r[2]=f2bf(a[2]); r[3]=f2bf(a[3]);
  r[4]=f2bf(b[0]); r[5]=f2bf(b[1]); r[6]=f2bf(b[2]); r[7]=f2bf(b[3]);
  return r;
}
__device__ __forceinline__ bf16x8 load8cvt(const float* p) {
  f32x4 a = *(const f32x4*)p;
  f32x4 b = *(const f32x4*)(p + 4);
  return cvt8(a, b);
}
__device__ __forceinline__ f32x4 mfma16(bf16x8 a, bf16x8 b, f32x4 c) {
  return __builtin_amdgcn_mfma_f32_16x16x32_bf16(a, b, c, 0, 0, 0);
}
// tanh(x) = 1 - 2/(1+e^{2x}); saturates correctly. 2 trans + 3 VALU.
__device__ __forceinline__ float fast_tanh(float x) {
  float e = __expf(2.0f * x);
  float r = __builtin_amdgcn_rcpf(1.0f + e);
  return 1.0f - 2.0f * r;
}
// fragment-major offset of element (k, row m) in a 16x256 bf16 tile.
__device__ __forceinline__ int frag_off(int k, int m) {
  return ((k >> 5) << 10) | (((k >> 3) & 3) << 8) | (m << 4) | ((k & 7) << 1);
}
__device__ __forceinline__ f32x4 unpk4(uint2 v) {
  f32x4 a;
  a[0] = __builtin_bit_cast(float, v.x << 16);
  a[1] = __builtin_bit_cast(float, v.x & 0xFFFF0000u);
  a[2] = __builtin_bit_cast(float, v.y << 16);
  a[3] = __builtin_bit_cast(float, v.y & 0xFFFF0000u);
  return a;
}

// ============ pre-pass: pre0[tile][t][ntile][lane] = x W_ih0^T + b (C-layout)
__global__ void __launch_bounds__(256)
x_proj(const float* __restrict__ x, const float* __restrict__ Wih0,
       const float* __restrict__ bih0, const float* __restrict__ bhh0,
       uint2* __restrict__ pre0) {
  const int tid = threadIdx.x, w = tid >> 6, l = tid & 63;
  const int lm = l & 15, lq = l >> 4;
  const int tile = blockIdx.x, tch = blockIdx.y;

  bf16x8 wih[4][2]; float bias[4];
#pragma unroll
  for (int i = 0; i < 4; ++i) {
    int n = ((w * 4 + i) << 4) + lm;
    wih[i][0] = load8cvt(Wih0 + n * DIN + lq * 8);
    wih[i][1] = load8cvt(Wih0 + n * DIN + 32 + lq * 8);
    bias[i] = bih0[n] + bhh0[n];
  }
  const float* xb = x + (size_t)(tile * 16 + lm) * (S_LEN * DIN) + lq * 8;
  for (int tt = 0; tt < 16; ++tt) {
    int t = tch * 16 + tt;
    const float* xp = xb + (size_t)t * DIN;
    bf16x8 xa0 = load8cvt(xp);
    bf16x8 xa1 = load8cvt(xp + 32);
    uint2* dst = pre0 + ((size_t)(tile * S_LEN + t) * 16 + w * 4) * 64 + l;
#pragma unroll
    for (int i = 0; i < 4; ++i) {
      f32x4 a = {bias[i], bias[i], bias[i], bias[i]};
      a = mfma16(xa0, wih[i][0], a);
      a = mfma16(xa1, wih[i][1], a);
      uint2 pk;
      pk.x = (unsigned)(unsigned short)f2bf(a[0]) | ((unsigned)(unsigned short)f2bf(a[1]) << 16);
      pk.y = (unsigned)(unsigned short)f2bf(a[2]) | ((unsigned)(unsigned short)f2bf(a[3]) << 16);
      dst[(size_t)i * 64] = pk;
    }
  }
}

// ============ persistent recurrence: 16 WGs x 512 thr (8 waves, 2/SIMD) =====
// smem: h0 ping 0 / pong 8192; h1 ping 16384 / pong 24576; epilogue 32768.
__global__ void __launch_bounds__(512, 2)
rnn_pre8(const float* __restrict__ Whh0, const float* __restrict__ Wih1,
         const float* __restrict__ Whh1, const float* __restrict__ bih1,
         const float* __restrict__ bhh1, const float* __restrict__ Wout,
         const float* __restrict__ bout, const uint2* __restrict__ pre0,
         float* __restrict__ out) {
  __shared__ __align__(16) char smem[33792];

  const int tid = threadIdx.x, w = tid >> 6, l = tid & 63;
  const int lm = l & 15, lq = l >> 4;
  const int tile = blockIdx.x;

  // 48 weight fragments / wave = 192 VGPRs (fits the 256-cap => no AGPR moves)
  bf16x8 whh0[2][8], wih1[2][8], whh1[2][8];
  float bias1[2];
#pragma unroll
  for (int i = 0; i < 2; ++i) {
    int n = ((w * 2 + i) << 4) + lm;
#pragma unroll
    for (int kt = 0; kt < 8; ++kt) {
      whh0[i][kt] = load8cvt(Whh0 + n * HDIM + kt * 32 + lq * 8);
      wih1[i][kt] = load8cvt(Wih1 + n * HDIM + kt * 32 + lq * 8);
      whh1[i][kt] = load8cvt(Whh1 + n * HDIM + kt * 32 + lq * 8);
    }
    bias1[i] = bih1[n] + bhh1[n];
  }
  // zero h1 pong (= h1[-1], offsets 24576..32767): 512 thr x 16B
  ((f32x4*)(smem + 24576))[tid] = (f32x4){0.f, 0.f, 0.f, 0.f};

  const int lbase = l << 4;                         // sole read-addr register
  const int wbase = frag_off(w * 32 + lm, lq << 2); // sole write-addr register

  // pre0 stream: per t, wave reads 2 uint2 at pbase[p*1024] / +64.
  const uint2* pbase = pre0 + (size_t)tile * (S_LEN * 1024) + w * 128 + l;
  uint2 bufA[2], bufB[2];                           // pre[t] double buffer
  bufA[0] = pbase[0];    bufA[1] = pbase[64];       // pre[0]
  bufB[0] = pbase[1024]; bufB[1] = pbase[1024 + 64];// pre[1]

  // ---- phase 0 (peeled, pbit=0): h0[0] = tanh(pre[0]) ---------------------
  {
#pragma unroll
    for (int i = 0; i < 2; ++i) {
      f32x4 a = unpk4(bufA[i]);
#pragma unroll
      for (int r = 0; r < 4; ++r)
        *(short*)(smem + wbase + i * 512 + r * 16) = f2bf(fast_tanh(a[r]));
    }
    const uint2* np = pbase + (size_t)2 * 1024;     // prefetch pre[2]
    bufA[0] = np[0]; bufA[1] = np[64];
    __syncthreads();
  }

  // ---- merged phase: h0[p] and h1[p-1]; pbit = p&1 (compile-time const) ---
  auto phase = [&](int p, int pbit, uint2 (&buf)[2]) {
    const int h0r_o = (pbit ^ 1) * 8192;
    const int h0w_o = pbit * 8192;
    const int h1r_o = 16384 + pbit * 8192;
    const int h1w_o = 16384 + (pbit ^ 1) * 8192;

    f32x4 a0 = unpk4(buf[0]), a1 = unpk4(buf[1]);   // pre[p] as C operand
    f32x4 c0 = {bias1[0], bias1[0], bias1[0], bias1[0]};
    f32x4 c1 = {bias1[1], bias1[1], bias1[1], bias1[1]};

#pragma unroll
    for (int kt = 0; kt < 8; ++kt) {                // shared h0[p-1] frags
      bf16x8 hf = *(const bf16x8*)(smem + h0r_o + kt * 1024 + lbase);
      a0 = mfma16(hf, whh0[0][kt], a0);
      a1 = mfma16(hf, whh0[1][kt], a1);
      c0 = mfma16(hf, wih1[0][kt], c0);
      c1 = mfma16(hf, wih1[1][kt], c1);
    }
#pragma unroll
    for (int kt = 0; kt < 8; ++kt) {                // h1[p-2] frags
      bf16x8 hf = *(const bf16x8*)(smem + h1r_o + kt * 1024 + lbase);
      c0 = mfma16(hf, whh1[0][kt], c0);
      c1 = mfma16(hf, whh1[1][kt], c1);
    }
#pragma unroll
    for (int i = 0; i < 2; ++i) {
      f32x4 a = i ? a1 : a0;
      f32x4 c = i ? c1 : c0;
#pragma unroll
      for (int r = 0; r < 4; ++r) {
        *(short*)(smem + h0w_o + wbase + i * 512 + r * 16) = f2bf(fast_tanh(a[r]));
        *(short*)(smem + h1w_o + wbase + i * 512 + r * 16) = f2bf(fast_tanh(c[r]));
      }
    }
    // prefetch pre[p+2] into the buffer just consumed (2-phase lookahead)
    {
      int tn = (p + 2 < S_LEN) ? p + 2 : S_LEN - 1;
      const uint2* np = pbase + (size_t)tn * 1024;
      buf[0] = np[0]; buf[1] = np[64];
    }
    __syncthreads();
  };

  for (int p = 1; p + 1 < S_LEN; p += 2) {          // p = 1..2046
    phase(p, 1, bufB);
    phase(p + 1, 0, bufA);
  }
  phase(S_LEN - 1, 1, bufB);                        // p = 2047

  // ---- tail phase (p=S): h1[S-1] ------------------------------------------
  {
    f32x4 c0 = {bias1[0], bias1[0], bias1[0], bias1[0]};
    f32x4 c1 = {bias1[1], bias1[1], bias1[1], bias1[1]};
#pragma unroll
    for (int kt = 0; kt < 8; ++kt) {                // h0[S-1] at parity 1
      bf16x8 hf = *(const bf16x8*)(smem + 8192 + kt * 1024 + lbase);
      c0 = mfma16(hf, wih1[0][kt], c0);
      c1 = mfma16(hf, wih1[1][kt], c1);
    }
#pragma unroll
    for (int kt = 0; kt < 8; ++kt) {                // h1[S-2] at parity 0
      bf16x8 hf = *(const bf16x8*)(smem + 16384 + kt * 1024 + lbase);
      c0 = mfma16(hf, whh1[0][kt], c0);
      c1 = mfma16(hf, whh1[1][kt], c1);
    }
#pragma unroll
    for (int i = 0; i < 2; ++i) {
      f32x4 c = i ? c1 : c0;
#pragma unroll
      for (int r = 0; r < 4; ++r)
        *(short*)(smem + 24576 + wbase + i * 512 + r * 16) = f2bf(fast_tanh(c[r]));
    }
    __syncthreads();
  }

  // ---- epilogue: out = sigmoid(h1[S-1] @ W_out^T + b_out); h1 at 24576 ----
  if (tid < 256) {
    int m = tid >> 4, j = tid & 15;
    float s = 0.f;
#pragma unroll
    for (int kk = 0; kk < 16; ++kk) {
      int k = j * 16 + kk;
      s += bf2f(*(unsigned short*)(smem + 24576 + frag_off(k, m))) * Wout[k];
    }
    ((float*)(smem + 32768))[(m << 4) + j] = s;
  }
  __syncthreads();
  if (tid < 16) {
    float s = 0.f;
#pragma unroll
    for (int j = 0; j < 16; ++j) s += ((float*)(smem + 32768))[(tid << 4) + j];
    s += bout[0];
    out[(tile << 4) + tid] = 1.f / (1.f + __expf(-s));
  }
}

// ============ fallback (small ws): R2-style fused inline-x, 8 waves =========
__global__ void __launch_bounds__(512)
rnn_inline(const float* __restrict__ x,
           const float* __restrict__ Wih0, const float* __restrict__ Whh0,
           const float* __restrict__ bih0, const float* __restrict__ bhh0,
           const float* __restrict__ Wih1, const float* __restrict__ Whh1,
           const float* __restrict__ bih1, const float* __restrict__ bhh1,
           const float* __restrict__ Wout, const float* __restrict__ bout,
           float* __restrict__ out) {
  __shared__ __align__(16) char smem[37888];

  const int tid = threadIdx.x, w = tid >> 6, l = tid & 63;
  const int lm = l & 15, lq = l >> 4;
  const int tile = blockIdx.x;

  bf16x8 whh0[2][8], wih0[2][2], wih1[2][8], whh1[2][8];
  float bias0[2], bias1[2];
#pragma unroll
  for (int i = 0; i < 2; ++i) {
    int n = ((w * 2 + i) << 4) + lm;
#pragma unroll
    for (int kt = 0; kt < 8; ++kt) {
      whh0[i][kt] = load8cvt(Whh0 + n * HDIM + kt * 32 + lq * 8);
      wih1[i][kt] = load8cvt(Wih1 + n * HDIM + kt * 32 + lq * 8);
      whh1[i][kt] = load8cvt(Whh1 + n * HDIM + kt * 32 + lq * 8);
    }
    wih0[i][0] = load8cvt(Wih0 + n * DIN + lq * 8);
    wih0[i][1] = load8cvt(Wih0 + n * DIN + 32 + lq * 8);
    bias0[i] = bih0[n] + bhh0[n];
    bias1[i] = bih1[n] + bhh1[n];
  }
  ((f32x4*)(smem + 24576))[tid] = (f32x4){0.f, 0.f, 0.f, 0.f};
  const float* xrow = x + (size_t)(tile * 16 + lm) * (S_LEN * DIN);
  if (w < 2)
    *(bf16x8*)(smem + 32768 + w * 1024 + (l << 4)) = load8cvt(xrow + w * 32 + lq * 8);
  __syncthreads();

  {
    f32x4 a0 = {bias0[0], bias0[0], bias0[0], bias0[0]};
    f32x4 a1 = {bias0[1], bias0[1], bias0[1], bias0[1]};
    bf16x8 xa0 = *(const bf16x8*)(smem + 32768 + (l << 4));
    bf16x8 xa1 = *(const bf16x8*)(smem + 32768 + 1024 + (l << 4));
    a0 = mfma16(xa0, wih0[0][0], a0); a0 = mfma16(xa1, wih0[0][1], a0);
    a1 = mfma16(xa0, wih0[1][0], a1); a1 = mfma16(xa1, wih0[1][1], a1);
    if (w < 2)
      *(bf16x8*)(smem + 34816 + w * 1024 + (l << 4)) = load8cvt(xrow + DIN + w * 32 + lq * 8);
#pragma unroll
    for (int i = 0; i < 2; ++i) {
      f32x4 a = i ? a1 : a0;
      int n = ((w * 2 + i) << 4) + lm;
#pragma unroll
      for (int r = 0; r < 4; ++r)
        *(short*)(smem + frag_off(n, (lq << 2) + r)) = f2bf(fast_tanh(a[r]));
    }
    __syncthreads();
  }

  for (int p = 1; p < S_LEN; ++p) {
    const int h0r_o = ((p - 1) & 1) * 8192;
    const int h0w_o = (p & 1) * 8192;
    const int h1r_o = 16384 + (p & 1) * 8192;
    const int h1w_o = 16384 + ((p - 1) & 1) * 8192;
    const int xsr_o = 32768 + (p & 1) * 2048;
    const int xsw_o = 32768 + ((p + 1) & 1) * 2048;

    f32x4 xl0, xl1;
    const bool hx = (w < 2) && (p + 1 < S_LEN);
    if (hx) {
      const float* xp = xrow + (size_t)(p + 1) * DIN + w * 32 + lq * 8;
      xl0 = *(const f32x4*)xp; xl1 = *(const f32x4*)(xp + 4);
    }
    f32x4 a0 = {bias0[0], bias0[0], bias0[0], bias0[0]};
    f32x4 a1 = {bias0[1], bias0[1], bias0[1], bias0[1]};
    f32x4 c0 = {bias1[0], bias1[0], bias1[0], bias1[0]};
    f32x4 c1 = {bias1[1], bias1[1], bias1[1], bias1[1]};
#pragma unroll
    for (int kt = 0; kt < 8; ++kt) {
      bf16x8 hf = *(const bf16x8*)(smem + h0r_o + kt * 1024 + (l << 4));
      a0 = mfma16(hf, whh0[0][kt], a0);
      a1 = mfma16(hf, whh0[1][kt], a1);
      c0 = mfma16(hf, wih1[0][kt], c0);
      c1 = mfma16(hf, wih1[1][kt], c1);
    }
    {
      bf16x8 xa0 = *(const bf16x8*)(smem + xsr_o + (l << 4));
      bf16x8 xa1 = *(const bf16x8*)(smem + xsr_o + 1024 + (l << 4));
      a0 = mfma16(xa0, wih0[0][0], a0); a0 = mfma16(xa1, wih0[0][1], a0);
      a1 = mfma16(xa0, wih0[1][0], a1); a1 = mfma16(xa1, wih0[1][1], a1);
    }
#pragma unroll
    for (int kt = 0; kt < 8; ++kt) {
      bf16x8 hf = *(const bf16x8*)(smem + h1r_o + kt * 1024 + (l << 4));
      c0 = mfma16(hf, whh1[0][kt], c0);
      c1 = mfma16(hf, whh1[1][kt], c1);
    }
    if (hx) *(bf16x8*)(smem + xsw_o + w * 1024 + (l << 4)) = cvt8(xl0, xl1);
#pragma unroll
    for (int i = 0; i < 2; ++i) {
      f32x4 a = i ? a1 : a0;
      f32x4 c = i ? c1 : c0;
      int n = ((w * 2 + i) << 4) + lm;
#pragma unroll
      for (int r = 0; r < 4; ++r) {
        int fo = frag_off(n, (lq << 2) + r);
        *(short*)(smem + h0w_o + fo) = f2bf(fast_tanh(a[r]));
        *(short*)(smem + h1w_o + fo) = f2bf(fast_tanh(c[r]));
      }
    }
    __syncthreads();
  }
  {
    const int h0r_o = ((S_LEN - 1) & 1) * 8192;
    const int h1r_o = 16384 + (S_LEN & 1) * 8192;
    const int h1w_o = 16384 + ((S_LEN - 1) & 1) * 8192;
    f32x4 c0 = {bias1[0], bias1[0], bias1[0], bias1[0]};
    f32x4 c1 = {bias1[1], bias1[1], bias1[1], bias1[1]};
#pragma unroll
    for (int kt = 0; kt < 8; ++kt) {
      bf16x8 hf = *(const bf16x8*)(smem + h0r_o + kt * 1024 + (l << 4));
      c0 = mfma16(hf, wih1[0][kt], c0);
      c1 = mfma16(hf, wih1[1][kt], c1);
    }
#pragma unroll
    for (int kt = 0; kt < 8; ++kt) {
      bf16x8 hf = *(const bf16x8*)(smem + h1r_o + kt * 1024 + (l << 4));
      c0 = mfma16(hf, whh1[0][kt], c0);
      c1 = mfma16(hf, whh1[1][kt], c1);
    }
#pragma unroll
    for (int i = 0; i < 2; ++i) {
      f32x4 c = i ? c1 : c0;
      int n = ((w * 2 + i) << 4) + lm;
#pragma unroll
      for (int r = 0; r < 4; ++r)
        *(short*)(smem + h1w_o + frag_off(n, (lq << 2) + r)) = f2bf(fast_tanh(c[r]));
    }
    __syncthreads();
  }
  if (tid < 256) {
    int m = tid >> 4, j = tid & 15;
    float s = 0.f;
#pragma unroll
    for (int kk = 0; kk < 16; ++kk) {
      int k = j * 16 + kk;
      s += bf2f(*(unsigned short*)(smem + 24576 + frag_off(k, m))) * Wout[k];
    }
    ((float*)(smem + 36864))[(m << 4) + j] = s;
  }
  __syncthreads();
  if (tid < 16) {
    float s = 0.f;
#pragma unroll
    for (int j = 0; j < 16; ++j) s += ((float*)(smem + 36864))[(tid << 4) + j];
    s += bout[0];
    out[(tile << 4) + tid] = 1.f / (1.f + __expf(-s));
  }
}

extern "C" void kernel_launch(void* const* d_in, const int* in_sizes, int n_in,
                              void* d_out, int out_size, void* d_ws, size_t ws_size,
                              hipStream_t stream) {
  (void)in_sizes; (void)n_in; (void)out_size;
  const float* x    = (const float*)d_in[0];
  const float* Wih0 = (const float*)d_in[1];
  const float* Whh0 = (const float*)d_in[2];
  const float* bih0 = (const float*)d_in[3];
  const float* bhh0 = (const float*)d_in[4];
  const float* Wih1 = (const float*)d_in[5];
  const float* Whh1 = (const float*)d_in[6];
  const float* bih1 = (const float*)d_in[7];
  const float* bhh1 = (const float*)d_in[8];
  const float* Wout = (const float*)d_in[9];
  const float* bout = (const float*)d_in[10];

  const size_t PRE_BYTES = (size_t)16 * S_LEN * 16 * 64 * 8;  // 268 MB
  if (ws_size >= PRE_BYTES) {
    x_proj<<<dim3(16, 128), dim3(256), 0, stream>>>(x, Wih0, bih0, bhh0,
                                                    (uint2*)d_ws);
    rnn_pre8<<<dim3(16), dim3(512), 0, stream>>>(
        Whh0, Wih1, Whh1, bih1, bhh1, Wout, bout, (const uint2*)d_ws,
        (float*)d_out);
  } else {
    rnn_inline<<<dim3(16), dim3(512), 0, stream>>>(
        x, Wih0, Whh0, bih0, bhh0, Wih1, Whh1, bih1, bhh1, Wout, bout,
        (float*)d_out);
  }
}

// Round 6
// 2218.596 us; speedup vs baseline: 2.4872x; 1.4422x over previous
//
#include <hip/hip_runtime.h>
#include <cstdint>

// ---------------------------------------------------------------------------
// 2-layer tanh RNN (B=256,S=2048,D=64,H=256).
// R5 (2.94ms) was LDS-read-bound: 8 waves x full-h re-read x 2 recurrences.
// R6: layer-pipelined, chunk-synced. One 32-WG launch:
//   Stage A (WG 0-15):  h0 recurrence + g[p-1]=h0[p-1]@Wih1^T+b1 (shares the
//                       h0 LDS reads), g stored IN-PLACE over consumed pre0
//                       slots; release-fence + flag every CH=64 steps.
//   Stage B (WG 16-31): h1 recurrence from g (global, 1-ahead prefetch),
//                       trails A by one chunk; epilogue sigmoid@W_out.
// A never waits on B (g has full-length storage) -> deadlock-free; agent-scope
// acquire/release makes it dispatch/XCD-assignment independent (G16).
// ---------------------------------------------------------------------------

#define S_LEN 2048
#define DIN   64
#define HDIM  256
#define CH    64        // chunk size (steps per cross-stage sync)

typedef __attribute__((ext_vector_type(8))) short bf16x8;
typedef __attribute__((ext_vector_type(4))) float f32x4;

__device__ __forceinline__ short f2bf(float f) {
  unsigned u = __builtin_bit_cast(unsigned, f);
  u += 0x7FFFu + ((u >> 16) & 1u);           // RNE
  return (short)(u >> 16);
}
__device__ __forceinline__ float bf2f(unsigned short h) {
  return __builtin_bit_cast(float, ((unsigned)h) << 16);
}
__device__ __forceinline__ bf16x8 cvt8(f32x4 a, f32x4 b) {
  bf16x8 r;
  r[0]=f2bf(a[0]); r[1]=f2bf(a[1]); r[2]=f2bf(a[2]); r[3]=f2bf(a[3]);
  r[4]=f2bf(b[0]); r[5]=f2bf(b[1]); r[6]=f2bf(b[2]); r[7]=f2bf(b[3]);
  return r;
}
__device__ __forceinline__ bf16x8 load8cvt(const float* p) {
  f32x4 a = *(const f32x4*)p;
  f32x4 b = *(const f32x4*)(p + 4);
  return cvt8(a, b);
}
__device__ __forceinline__ f32x4 mfma16(bf16x8 a, bf16x8 b, f32x4 c) {
  return __builtin_amdgcn_mfma_f32_16x16x32_bf16(a, b, c, 0, 0, 0);
}
__device__ __forceinline__ float fast_tanh(float x) {
  float e = __expf(2.0f * x);
  float r = __builtin_amdgcn_rcpf(1.0f + e);
  return 1.0f - 2.0f * r;
}
__device__ __forceinline__ int frag_off(int k, int m) {
  return ((k >> 5) << 10) | (((k >> 3) & 3) << 8) | (m << 4) | ((k & 7) << 1);
}
__device__ __forceinline__ f32x4 unpk4(uint2 v) {
  f32x4 a;
  a[0] = __builtin_bit_cast(float, v.x << 16);
  a[1] = __builtin_bit_cast(float, v.x & 0xFFFF0000u);
  a[2] = __builtin_bit_cast(float, v.y << 16);
  a[3] = __builtin_bit_cast(float, v.y & 0xFFFF0000u);
  return a;
}
__device__ __forceinline__ uint2 pk4(f32x4 a) {
  uint2 p;
  p.x = (unsigned)(unsigned short)f2bf(a[0]) | ((unsigned)(unsigned short)f2bf(a[1]) << 16);
  p.y = (unsigned)(unsigned short)f2bf(a[2]) | ((unsigned)(unsigned short)f2bf(a[3]) << 16);
  return p;
}
__device__ __forceinline__ unsigned ld_acq(unsigned* p) {
  return __hip_atomic_load(p, __ATOMIC_ACQUIRE, __HIP_MEMORY_SCOPE_AGENT);
}
__device__ __forceinline__ void st_rlx(unsigned* p, unsigned v) {
  __hip_atomic_store(p, v, __ATOMIC_RELAXED, __HIP_MEMORY_SCOPE_AGENT);
}

__global__ void zero_flags(unsigned* f) {
  if (threadIdx.x < 64) f[threadIdx.x] = 0u;
}

// ============ pre-pass: pre0[tile][t][ntile][lane] = x W_ih0^T + b (C-layout)
__global__ void __launch_bounds__(256)
x_proj(const float* __restrict__ x, const float* __restrict__ Wih0,
       const float* __restrict__ bih0, const float* __restrict__ bhh0,
       uint2* __restrict__ pre0) {
  const int tid = threadIdx.x, w = tid >> 6, l = tid & 63;
  const int lm = l & 15, lq = l >> 4;
  const int tile = blockIdx.x, tch = blockIdx.y;

  bf16x8 wih[4][2]; float bias[4];
#pragma unroll
  for (int i = 0; i < 4; ++i) {
    int n = ((w * 4 + i) << 4) + lm;
    wih[i][0] = load8cvt(Wih0 + n * DIN + lq * 8);
    wih[i][1] = load8cvt(Wih0 + n * DIN + 32 + lq * 8);
    bias[i] = bih0[n] + bhh0[n];
  }
  const float* xb = x + (size_t)(tile * 16 + lm) * (S_LEN * DIN) + lq * 8;
  for (int tt = 0; tt < 16; ++tt) {
    int t = tch * 16 + tt;
    const float* xp = xb + (size_t)t * DIN;
    bf16x8 xa0 = load8cvt(xp);
    bf16x8 xa1 = load8cvt(xp + 32);
    uint2* dst = pre0 + ((size_t)(tile * S_LEN + t) * 16 + w * 4) * 64 + l;
#pragma unroll
    for (int i = 0; i < 4; ++i) {
      f32x4 a = {bias[i], bias[i], bias[i], bias[i]};
      a = mfma16(xa0, wih[i][0], a);
      a = mfma16(xa1, wih[i][1], a);
      dst[(size_t)i * 64] = pk4(a);
    }
  }
}

// ============ layer-pipelined recurrence: 32 WGs x 512 thr ==================
// Stage A LDS: h0 ping 0 / pong 8192.
// Stage B LDS: h1 ping 0 / pong 8192; epilogue scratch 16384.
__global__ void __launch_bounds__(512, 2)
rnn_pipe2(const float* __restrict__ Whh0, const float* __restrict__ Wih1,
          const float* __restrict__ Whh1, const float* __restrict__ bih1,
          const float* __restrict__ bhh1, const float* __restrict__ Wout,
          const float* __restrict__ bout, uint2* __restrict__ pre0,
          unsigned* __restrict__ flags, float* __restrict__ out) {
  __shared__ __align__(16) char smem[17408];

  const int tid = threadIdx.x, w = tid >> 6, l = tid & 63;
  const int lm = l & 15, lq = l >> 4;
  const int role = blockIdx.x >> 4;       // 0=A (layer0+g), 1=B (layer1)
  const int tile = blockIdx.x & 15;       // A(t) and B(t) land on same XCD (%8)

  const int lbase = l << 4;
  const int wbase = frag_off(w * 32 + lm, lq << 2);
  uint2* pb = pre0 + (size_t)tile * (S_LEN * 1024) + w * 128 + l;
  unsigned* flag = flags + tile;

  if (role == 0) {
    // ================= Stage A: h0 recurrence + g producer ==================
    bf16x8 whh0[2][8], wih1[2][8];
    float bias1[2];
#pragma unroll
    for (int i = 0; i < 2; ++i) {
      int n = ((w * 2 + i) << 4) + lm;
#pragma unroll
      for (int kt = 0; kt < 8; ++kt) {
        whh0[i][kt] = load8cvt(Whh0 + n * HDIM + kt * 32 + lq * 8);
        wih1[i][kt] = load8cvt(Wih1 + n * HDIM + kt * 32 + lq * 8);
      }
      bias1[i] = bih1[n] + bhh1[n];
    }
    uint2 bufA[2], bufB[2];
    bufA[0] = pb[0];    bufA[1] = pb[64];        // pre[0]
    bufB[0] = pb[1024]; bufB[1] = pb[1024 + 64]; // pre[1]

    // phase 0 (peeled): h0[0] = tanh(pre[0]) into parity-0 buffer
    {
#pragma unroll
      for (int i = 0; i < 2; ++i) {
        f32x4 a = unpk4(bufA[i]);
#pragma unroll
        for (int r = 0; r < 4; ++r)
          *(short*)(smem + wbase + i * 512 + r * 16) = f2bf(fast_tanh(a[r]));
      }
      const uint2* np = pb + (size_t)2 * 1024;   // prefetch pre[2]
      bufA[0] = np[0]; bufA[1] = np[64];
      __syncthreads();
    }

    // phase p: h0[p] = tanh(pre[p] + h0[p-1]Whh0^T), g[p-1] = h0[p-1]Wih1^T+b1
    auto phaseA = [&](int p, int pbit, uint2 (&buf)[2]) {
      const int h0r = (pbit ^ 1) * 8192;
      const int h0w = pbit * 8192;
      f32x4 a0 = unpk4(buf[0]), a1 = unpk4(buf[1]);
      f32x4 g0 = {bias1[0], bias1[0], bias1[0], bias1[0]};
      f32x4 g1 = {bias1[1], bias1[1], bias1[1], bias1[1]};
#pragma unroll
      for (int kt = 0; kt < 8; ++kt) {           // shared h0[p-1] read
        bf16x8 hf = *(const bf16x8*)(smem + h0r + kt * 1024 + lbase);
        a0 = mfma16(hf, whh0[0][kt], a0);
        a1 = mfma16(hf, whh0[1][kt], a1);
        g0 = mfma16(hf, wih1[0][kt], g0);
        g1 = mfma16(hf, wih1[1][kt], g1);
      }
      {                                          // prefetch pre[p+2] (clamped)
        int tn = (p + 2 < S_LEN) ? p + 2 : S_LEN - 1;
        const uint2* np = pb + (size_t)tn * 1024;
        buf[0] = np[0]; buf[1] = np[64];
      }
#pragma unroll
      for (int i = 0; i < 2; ++i) {              // write h0[p] to LDS
        f32x4 a = i ? a1 : a0;
#pragma unroll
        for (int r = 0; r < 4; ++r)
          *(short*)(smem + h0w + wbase + i * 512 + r * 16) = f2bf(fast_tanh(a[r]));
      }
      {                                          // g[p-1] in-place over pre0
        uint2* gd = pb + (size_t)(p - 1) * 1024;
        gd[0] = pk4(g0); gd[64] = pk4(g1);
      }
      if ((p & (CH - 1)) == 0)                   // chunk p/CH-1 complete
        __builtin_amdgcn_fence(__ATOMIC_RELEASE, "agent");
      __syncthreads();
      if ((p & (CH - 1)) == 0 && tid == 0) st_rlx(flag, (unsigned)(p >> 6));
    };

    for (int p = 1; p + 1 < S_LEN; p += 2) {
      phaseA(p, 1, bufB);
      phaseA(p + 1, 0, bufA);
    }
    phaseA(S_LEN - 1, 1, bufB);                  // p = 2047

    // tail: g[S-1] = h0[S-1]Wih1^T + b1  (h0[2047] at parity 1)
    {
      f32x4 g0 = {bias1[0], bias1[0], bias1[0], bias1[0]};
      f32x4 g1 = {bias1[1], bias1[1], bias1[1], bias1[1]};
#pragma unroll
      for (int kt = 0; kt < 8; ++kt) {
        bf16x8 hf = *(const bf16x8*)(smem + 8192 + kt * 1024 + lbase);
        g0 = mfma16(hf, wih1[0][kt], g0);
        g1 = mfma16(hf, wih1[1][kt], g1);
      }
      uint2* gd = pb + (size_t)(S_LEN - 1) * 1024;
      gd[0] = pk4(g0); gd[64] = pk4(g1);
      __builtin_amdgcn_fence(__ATOMIC_RELEASE, "agent");
      __syncthreads();
      if (tid == 0) st_rlx(flag, (unsigned)(S_LEN / CH));   // = 32
    }

  } else {
    // ================= Stage B: h1 recurrence + output ======================
    bf16x8 whh1[2][8];
#pragma unroll
    for (int i = 0; i < 2; ++i) {
      int n = ((w * 2 + i) << 4) + lm;
#pragma unroll
      for (int kt = 0; kt < 8; ++kt)
        whh1[i][kt] = load8cvt(Whh1 + n * HDIM + kt * 32 + lq * 8);
    }
    // zero h1[-1] (parity-1 buffer at 8192): 512 thr x 16B = 8KB
    ((f32x4*)(smem + 8192))[tid] = (f32x4){0.f, 0.f, 0.f, 0.f};
    __syncthreads();

    uint2 gcur[2], gnxt[2];
    unsigned have = 0;

    auto stepB = [&](int t, int pbit) {
      const int h1r = (pbit ^ 1) * 8192;
      const int h1w = pbit * 8192;
      const bool pf = ((t & (CH - 1)) != CH - 1);  // next g within this chunk
      if (pf) {
        const uint2* np = pb + (size_t)(t + 1) * 1024;
        gnxt[0] = np[0]; gnxt[1] = np[64];
      }
      f32x4 c0 = unpk4(gcur[0]), c1 = unpk4(gcur[1]);
#pragma unroll
      for (int kt = 0; kt < 8; ++kt) {
        bf16x8 hf = *(const bf16x8*)(smem + h1r + kt * 1024 + lbase);
        c0 = mfma16(hf, whh1[0][kt], c0);
        c1 = mfma16(hf, whh1[1][kt], c1);
      }
#pragma unroll
      for (int i = 0; i < 2; ++i) {
        f32x4 c = i ? c1 : c0;
#pragma unroll
        for (int r = 0; r < 4; ++r)
          *(short*)(smem + h1w + wbase + i * 512 + r * 16) = f2bf(fast_tanh(c[r]));
      }
      if (pf) { gcur[0] = gnxt[0]; gcur[1] = gnxt[1]; }
      __syncthreads();
    };

    for (int c = 0; c < S_LEN / CH; ++c) {
      while (have < (unsigned)(c + 1)) {           // per-chunk acquire wait
        have = ld_acq(flag);
        if (have < (unsigned)(c + 1)) __builtin_amdgcn_s_sleep(8);
      }
      const int t0 = c * CH;
      { const uint2* np = pb + (size_t)t0 * 1024; gcur[0] = np[0]; gcur[1] = np[64]; }
      for (int tt = 0; tt < CH; tt += 2) {
        stepB(t0 + tt, 0);
        stepB(t0 + tt + 1, 1);
      }
    }

    // epilogue: out = sigmoid(h1[S-1] @ W_out^T + b_out); h1[2047] at 8192
    if (tid < 256) {
      int m = tid >> 4, j = tid & 15;
      float s = 0.f;
#pragma unroll
      for (int kk = 0; kk < 16; ++kk) {
        int k = j * 16 + kk;
        s += bf2f(*(unsigned short*)(smem + 8192 + frag_off(k, m))) * Wout[k];
      }
      ((float*)(smem + 16384))[(m << 4) + j] = s;
    }
    __syncthreads();
    if (tid < 16) {
      float s = 0.f;
#pragma unroll
      for (int j = 0; j < 16; ++j) s += ((float*)(smem + 16384))[(tid << 4) + j];
      s += bout[0];
      out[(tile << 4) + tid] = 1.f / (1.f + __expf(-s));
    }
  }
}

// ============ fallback (ws too small for flags): R5 single-stage ============
__global__ void __launch_bounds__(512, 2)
rnn_pre8(const float* __restrict__ Whh0, const float* __restrict__ Wih1,
         const float* __restrict__ Whh1, const float* __restrict__ bih1,
         const float* __restrict__ bhh1, const float* __restrict__ Wout,
         const float* __restrict__ bout, const uint2* __restrict__ pre0,
         float* __restrict__ out) {
  __shared__ __align__(16) char smem[33792];

  const int tid = threadIdx.x, w = tid >> 6, l = tid & 63;
  const int lm = l & 15, lq = l >> 4;
  const int tile = blockIdx.x;

  bf16x8 whh0[2][8], wih1[2][8], whh1[2][8];
  float bias1[2];
#pragma unroll
  for (int i = 0; i < 2; ++i) {
    int n = ((w * 2 + i) << 4) + lm;
#pragma unroll
    for (int kt = 0; kt < 8; ++kt) {
      whh0[i][kt] = load8cvt(Whh0 + n * HDIM + kt * 32 + lq * 8);
      wih1[i][kt] = load8cvt(Wih1 + n * HDIM + kt * 32 + lq * 8);
      whh1[i][kt] = load8cvt(Whh1 + n * HDIM + kt * 32 + lq * 8);
    }
    bias1[i] = bih1[n] + bhh1[n];
  }
  ((f32x4*)(smem + 24576))[tid] = (f32x4){0.f, 0.f, 0.f, 0.f};

  const int lbase = l << 4;
  const int wbase = frag_off(w * 32 + lm, lq << 2);
  const uint2* pbase = pre0 + (size_t)tile * (S_LEN * 1024) + w * 128 + l;
  uint2 bufA[2], bufB[2];
  bufA[0] = pbase[0];    bufA[1] = pbase[64];
  bufB[0] = pbase[1024]; bufB[1] = pbase[1024 + 64];

  {
#pragma unroll
    for (int i = 0; i < 2; ++i) {
      f32x4 a = unpk4(bufA[i]);
#pragma unroll
      for (int r = 0; r < 4; ++r)
        *(short*)(smem + wbase + i * 512 + r * 16) = f2bf(fast_tanh(a[r]));
    }
    const uint2* np = pbase + (size_t)2 * 1024;
    bufA[0] = np[0]; bufA[1] = np[64];
    __syncthreads();
  }

  auto phase = [&](int p, int pbit, uint2 (&buf)[2]) {
    const int h0r_o = (pbit ^ 1) * 8192;
    const int h0w_o = pbit * 8192;
    const int h1r_o = 16384 + pbit * 8192;
    const int h1w_o = 16384 + (pbit ^ 1) * 8192;

    f32x4 a0 = unpk4(buf[0]), a1 = unpk4(buf[1]);
    f32x4 c0 = {bias1[0], bias1[0], bias1[0], bias1[0]};
    f32x4 c1 = {bias1[1], bias1[1], bias1[1], bias1[1]};
#pragma unroll
    for (int kt = 0; kt < 8; ++kt) {
      bf16x8 hf = *(const bf16x8*)(smem + h0r_o + kt * 1024 + lbase);
      a0 = mfma16(hf, whh0[0][kt], a0);
      a1 = mfma16(hf, whh0[1][kt], a1);
      c0 = mfma16(hf, wih1[0][kt], c0);
      c1 = mfma16(hf, wih1[1][kt], c1);
    }
#pragma unroll
    for (int kt = 0; kt < 8; ++kt) {
      bf16x8 hf = *(const bf16x8*)(smem + h1r_o + kt * 1024 + lbase);
      c0 = mfma16(hf, whh1[0][kt], c0);
      c1 = mfma16(hf, whh1[1][kt], c1);
    }
#pragma unroll
    for (int i = 0; i < 2; ++i) {
      f32x4 a = i ? a1 : a0;
      f32x4 c = i ? c1 : c0;
#pragma unroll
      for (int r = 0; r < 4; ++r) {
        *(short*)(smem + h0w_o + wbase + i * 512 + r * 16) = f2bf(fast_tanh(a[r]));
        *(short*)(smem + h1w_o + wbase + i * 512 + r * 16) = f2bf(fast_tanh(c[r]));
      }
    }
    {
      int tn = (p + 2 < S_LEN) ? p + 2 : S_LEN - 1;
      const uint2* np = pbase + (size_t)tn * 1024;
      buf[0] = np[0]; buf[1] = np[64];
    }
    __syncthreads();
  };

  for (int p = 1; p + 1 < S_LEN; p += 2) {
    phase(p, 1, bufB);
    phase(p + 1, 0, bufA);
  }
  phase(S_LEN - 1, 1, bufB);

  {
    f32x4 c0 = {bias1[0], bias1[0], bias1[0], bias1[0]};
    f32x4 c1 = {bias1[1], bias1[1], bias1[1], bias1[1]};
#pragma unroll
    for (int kt = 0; kt < 8; ++kt) {
      bf16x8 hf = *(const bf16x8*)(smem + 8192 + kt * 1024 + lbase);
      c0 = mfma16(hf, wih1[0][kt], c0);
      c1 = mfma16(hf, wih1[1][kt], c1);
    }
#pragma unroll
    for (int kt = 0; kt < 8; ++kt) {
      bf16x8 hf = *(const bf16x8*)(smem + 16384 + kt * 1024 + lbase);
      c0 = mfma16(hf, whh1[0][kt], c0);
      c1 = mfma16(hf, whh1[1][kt], c1);
    }
#pragma unroll
    for (int i = 0; i < 2; ++i) {
      f32x4 c = i ? c1 : c0;
#pragma unroll
      for (int r = 0; r < 4; ++r)
        *(short*)(smem + 24576 + wbase + i * 512 + r * 16) = f2bf(fast_tanh(c[r]));
    }
    __syncthreads();
  }

  if (tid < 256) {
    int m = tid >> 4, j = tid & 15;
    float s = 0.f;
#pragma unroll
    for (int kk = 0; kk < 16; ++kk) {
      int k = j * 16 + kk;
      s += bf2f(*(unsigned short*)(smem + 24576 + frag_off(k, m))) * Wout[k];
    }
    ((float*)(smem + 32768))[(m << 4) + j] = s;
  }
  __syncthreads();
  if (tid < 16) {
    float s = 0.f;
#pragma unroll
    for (int j = 0; j < 16; ++j) s += ((float*)(smem + 32768))[(tid << 4) + j];
    s += bout[0];
    out[(tile << 4) + tid] = 1.f / (1.f + __expf(-s));
  }
}

extern "C" void kernel_launch(void* const* d_in, const int* in_sizes, int n_in,
                              void* d_out, int out_size, void* d_ws, size_t ws_size,
                              hipStream_t stream) {
  (void)in_sizes; (void)n_in; (void)out_size;
  const float* x    = (const float*)d_in[0];
  const float* Wih0 = (const float*)d_in[1];
  const float* Whh0 = (const float*)d_in[2];
  const float* bih0 = (const float*)d_in[3];
  const float* bhh0 = (const float*)d_in[4];
  const float* Wih1 = (const float*)d_in[5];
  const float* Whh1 = (const float*)d_in[6];
  const float* bih1 = (const float*)d_in[7];
  const float* bhh1 = (const float*)d_in[8];
  const float* Wout = (const float*)d_in[9];
  const float* bout = (const float*)d_in[10];

  const size_t PRE_BYTES = (size_t)16 * S_LEN * 16 * 64 * 8;  // 268 MB

  x_proj<<<dim3(16, 128), dim3(256), 0, stream>>>(x, Wih0, bih0, bhh0,
                                                  (uint2*)d_ws);
  if (ws_size >= PRE_BYTES + 4096) {
    unsigned* flags = (unsigned*)((char*)d_ws + PRE_BYTES);
    zero_flags<<<dim3(1), dim3(64), 0, stream>>>(flags);
    rnn_pipe2<<<dim3(32), dim3(512), 0, stream>>>(
        Whh0, Wih1, Whh1, bih1, bhh1, Wout, bout, (uint2*)d_ws, flags,
        (float*)d_out);
  } else {
    rnn_pre8<<<dim3(16), dim3(512), 0, stream>>>(
        Whh0, Wih1, Whh1, bih1, bhh1, Wout, bout, (const uint2*)d_ws,
        (float*)d_out);
  }
}